// Round 1
// baseline (69.780 us; speedup 1.0000x reference)
//
#include <hip/hip_runtime.h>
#include <hip/hip_bf16.h>

// GraphConvolution: out[b] = adj[b] @ (feat[b] @ W) + bias
// B=32, N=1024, IN=256, OUT=256. fp32 in/out, bf16 MFMA internally.
//
// ws layout: [0, 128KB)  Wt  = W^T as bf16 [n=256][k=256]
//            [128KB, ..) St  = support^T as bf16 [b][n=256][m=1024]  (16.78 MB)

typedef __attribute__((__ext_vector_type__(4))) float  f32x4;
typedef __attribute__((__ext_vector_type__(8))) __bf16 bf16x8;
typedef __attribute__((__ext_vector_type__(4))) __bf16 bf16x4;

#define NB   32
#define NN   1024
#define KIN  256
#define KOUT 256

// ---- weight transpose: w[k][n] fp32 -> Wt[n][k] bf16 -----------------------
__global__ __launch_bounds__(256) void k_wt(const float* __restrict__ w,
                                            __bf16* __restrict__ Wt) {
  __shared__ __bf16 T[64][65];
  const int bi = blockIdx.x >> 2;  // k tile
  const int bj = blockIdx.x & 3;   // n tile
  const int t  = threadIdx.x;
  const int r  = t >> 2;           // 0..63
  const int q  = t & 3;            // 0..3
  const float* src = w + (size_t)(bi * 64 + r) * KOUT + bj * 64 + q * 16;
#pragma unroll
  for (int u = 0; u < 4; ++u) {
    f32x4 v = *(const f32x4*)(src + u * 4);
    T[r][q * 16 + u * 4 + 0] = (__bf16)v.x;
    T[r][q * 16 + u * 4 + 1] = (__bf16)v.y;
    T[r][q * 16 + u * 4 + 2] = (__bf16)v.z;
    T[r][q * 16 + u * 4 + 3] = (__bf16)v.w;
  }
  __syncthreads();
  bf16x8 h0, h1;
#pragma unroll
  for (int u = 0; u < 8; ++u) {
    h0[u] = T[q * 16 + u][r];
    h1[u] = T[q * 16 + 8 + u][r];
  }
  __bf16* dst = Wt + (size_t)(bj * 64 + r) * KIN + bi * 64 + q * 16;
  *(bf16x8*)(dst)     = h0;
  *(bf16x8*)(dst + 8) = h1;
}

// ---- shared GEMM geometry: 128x256 block tile, BK=32, 512 thr (8 waves) ----
// wave wv: wr=wv>>2 (0..1), wc=wv&3 (0..3); wave tile 64x64; acc 4x4 frags.
// MFMA 16x16x32 bf16. A-frag: row lane&15, k-chunk (lane>>4)*8 (contiguous 8).
// C/D: col = lane&15, row = (lane>>4)*4 + reg.

// GEMM1: St^T[b][n][m] = (feat @ W)^T, bf16 out
__global__ __launch_bounds__(512) void k_gemm1(const float* __restrict__ F,
                                               const __bf16* __restrict__ Wt,
                                               __bf16* __restrict__ St) {
  __shared__ __bf16 As[128 * 32];
  __shared__ __bf16 Bs[256 * 32];
  const int tid  = threadIdx.x;
  const int lane = tid & 63;
  const int wv   = tid >> 6;
  const int wr   = wv >> 2;
  const int wc   = wv & 3;
  const int l16  = lane & 15;
  const int kch  = (lane >> 4) * 8;

  const int    bm = blockIdx.x;          // 0..255
  const size_t m0 = (size_t)bm * 128;

  f32x4 acc[4][4];
#pragma unroll
  for (int m = 0; m < 4; ++m)
#pragma unroll
    for (int n = 0; n < 4; ++n) acc[m][n] = (f32x4){0.f, 0.f, 0.f, 0.f};

  const int arow = tid >> 3;       // 0..63
  const int acol = (tid & 7) * 4;  // 0..28

  for (int k0 = 0; k0 < KIN; k0 += 32) {
    // stage A: 128x32 fp32 -> bf16
#pragma unroll
    for (int i = 0; i < 2; ++i) {
      const int r = arow + i * 64;
      f32x4 v = *(const f32x4*)(F + (m0 + r) * KIN + k0 + acol);
      bf16x4 h = {(__bf16)v.x, (__bf16)v.y, (__bf16)v.z, (__bf16)v.w};
      *(bf16x4*)&As[r * 32 + acol] = h;
    }
    // stage B: Wt[n][k] 256x32 bf16 copy
#pragma unroll
    for (int i = 0; i < 2; ++i) {
      const int cid = tid + i * 512;
      const int r   = cid >> 2;
      const int q   = (cid & 3) * 8;
      *(bf16x8*)&Bs[r * 32 + q] = *(const bf16x8*)(Wt + (size_t)r * KIN + k0 + q);
    }
    __syncthreads();
    bf16x8 af[4], bfv[4];
#pragma unroll
    for (int m = 0; m < 4; ++m)
      af[m] = *(const bf16x8*)&As[(wr * 64 + m * 16 + l16) * 32 + kch];
#pragma unroll
    for (int n = 0; n < 4; ++n)
      bfv[n] = *(const bf16x8*)&Bs[(wc * 64 + n * 16 + l16) * 32 + kch];
#pragma unroll
    for (int m = 0; m < 4; ++m)
#pragma unroll
      for (int n = 0; n < 4; ++n)
        acc[m][n] = __builtin_amdgcn_mfma_f32_16x16x32_bf16(af[m], bfv[n], acc[m][n], 0, 0, 0);
    __syncthreads();
  }

  // epilogue: St[b][n][m], b = bm>>3, m base = (bm&7)*128
  const int b     = bm >> 3;
  const int mbase = (bm & 7) * 128;
  const int rg    = (lane >> 4) * 4;
#pragma unroll
  for (int n = 0; n < 4; ++n) {
    const int col = wc * 64 + n * 16 + l16;  // n index
    __bf16* dst = St + ((size_t)b * 256 + col) * 1024 + mbase;
#pragma unroll
    for (int m = 0; m < 4; ++m) {
      const int row = wr * 64 + m * 16 + rg;
      bf16x4 h = {(__bf16)acc[m][n][0], (__bf16)acc[m][n][1],
                  (__bf16)acc[m][n][2], (__bf16)acc[m][n][3]};
      *(bf16x4*)(dst + row) = h;
    }
  }
}

// GEMM2: out[b] = adj[b] @ support[b] + bias  (A fp32->bf16, B=St bf16)
__global__ __launch_bounds__(512) void k_gemm2(const float* __restrict__ Adj,
                                               const __bf16* __restrict__ St,
                                               const float* __restrict__ bias,
                                               float* __restrict__ Out) {
  __shared__ __bf16 As[128 * 32];
  __shared__ __bf16 Bs[256 * 32];
  const int tid  = threadIdx.x;
  const int lane = tid & 63;
  const int wv   = tid >> 6;
  const int wr   = wv >> 2;
  const int wc   = wv & 3;
  const int l16  = lane & 15;
  const int kch  = (lane >> 4) * 8;

  // XCD-chunked swizzle (nwg=256, %8==0): batch-mates share an XCD's L2
  const int h  = blockIdx.x;
  const int lg = (h & 7) * 32 + (h >> 3);
  const int b  = lg >> 3;
  const int mt = lg & 7;
  const int m0 = mt * 128;

  const float*  Ab = Adj + (size_t)b * NN * NN;
  const __bf16* Bb = St + (size_t)b * 256 * 1024;

  f32x4 acc[4][4];
#pragma unroll
  for (int m = 0; m < 4; ++m)
#pragma unroll
    for (int n = 0; n < 4; ++n) acc[m][n] = (f32x4){0.f, 0.f, 0.f, 0.f};

  const int arow = tid >> 3;
  const int acol = (tid & 7) * 4;

  for (int k0 = 0; k0 < NN; k0 += 32) {
#pragma unroll
    for (int i = 0; i < 2; ++i) {
      const int r = arow + i * 64;
      f32x4 v = *(const f32x4*)(Ab + (size_t)(m0 + r) * NN + k0 + acol);
      bf16x4 hh = {(__bf16)v.x, (__bf16)v.y, (__bf16)v.z, (__bf16)v.w};
      *(bf16x4*)&As[r * 32 + acol] = hh;
    }
#pragma unroll
    for (int i = 0; i < 2; ++i) {
      const int cid = tid + i * 512;
      const int r   = cid >> 2;
      const int q   = (cid & 3) * 8;
      *(bf16x8*)&Bs[r * 32 + q] = *(const bf16x8*)(Bb + (size_t)r * 1024 + k0 + q);
    }
    __syncthreads();
    bf16x8 af[4], bfv[4];
#pragma unroll
    for (int m = 0; m < 4; ++m)
      af[m] = *(const bf16x8*)&As[(wr * 64 + m * 16 + l16) * 32 + kch];
#pragma unroll
    for (int n = 0; n < 4; ++n)
      bfv[n] = *(const bf16x8*)&Bs[(wc * 64 + n * 16 + l16) * 32 + kch];
#pragma unroll
    for (int m = 0; m < 4; ++m)
#pragma unroll
      for (int n = 0; n < 4; ++n)
        acc[m][n] = __builtin_amdgcn_mfma_f32_16x16x32_bf16(af[m], bfv[n], acc[m][n], 0, 0, 0);
    __syncthreads();
  }

  const int rg = (lane >> 4) * 4;
  float* ob = Out + ((size_t)b * 1024 + m0) * 256;
#pragma unroll
  for (int n = 0; n < 4; ++n) {
    const int col = wc * 64 + n * 16 + l16;
    const float bv = bias[col];
#pragma unroll
    for (int m = 0; m < 4; ++m) {
      const int row = wr * 64 + m * 16 + rg;
#pragma unroll
      for (int r2 = 0; r2 < 4; ++r2)
        ob[(size_t)(row + r2) * 256 + col] = acc[m][n][r2] + bv;
    }
  }
}

extern "C" void kernel_launch(void* const* d_in, const int* in_sizes, int n_in,
                              void* d_out, int out_size, void* d_ws, size_t ws_size,
                              hipStream_t stream) {
  const float* adj  = (const float*)d_in[0];
  const float* feat = (const float*)d_in[1];
  const float* w    = (const float*)d_in[2];
  const float* bias = (const float*)d_in[3];
  float* out = (float*)d_out;

  __bf16* Wt = (__bf16*)d_ws;                    // 131072 B
  __bf16* St = (__bf16*)((char*)d_ws + 131072);  // 16.78 MB

  k_wt<<<16, 256, 0, stream>>>(w, Wt);
  k_gemm1<<<256, 512, 0, stream>>>(feat, Wt, St);
  k_gemm2<<<256, 512, 0, stream>>>(adj, St, bias, out);
}

// Round 2
// 66.196 us; speedup vs baseline: 1.0541x; 1.0541x over previous
//
#include <hip/hip_runtime.h>
#include <hip/hip_bf16.h>

// GraphConvolution: out[b] = adj[b] @ (feat[b] @ W) + bias
// B=32, N=1024, IN=256, OUT=256. fp32 in/out, bf16 MFMA internally.
//
// ws: [0,128KB) Wt = W^T bf16 [n=256][k=256]
//     [128KB..) St = support^T bf16 [b][n=256][m=1024]
//
// GEMM template: 128x256 block tile, BK=64, 512 thr (8 waves, 2x4),
// double-buffered LDS, prefetch-1 (issue loads early, cvt+ds_write late),
// padded LDS rows (72 bf16 = 144B) for conflict-free ds_read_b128.

typedef __attribute__((__ext_vector_type__(4))) float  f32x4;
typedef __attribute__((__ext_vector_type__(8))) __bf16 bf16x8;
typedef __attribute__((__ext_vector_type__(4))) __bf16 bf16x4;

#define LDP 72  // padded LDS leading dim (elements): 144B rows, 16B-aligned

// ---- weight transpose: w[k][n] fp32 -> Wt[n][k] bf16 -----------------------
__global__ __launch_bounds__(256) void k_wt(const float* __restrict__ w,
                                            __bf16* __restrict__ Wt) {
  __shared__ __bf16 T[64][65];
  const int bi = blockIdx.x >> 2;  // k tile
  const int bj = blockIdx.x & 3;   // n tile
  const int t  = threadIdx.x;
  const int r  = t >> 2;
  const int q  = t & 3;
  const float* src = w + (size_t)(bi * 64 + r) * 256 + bj * 64 + q * 16;
#pragma unroll
  for (int u = 0; u < 4; ++u) {
    f32x4 v = *(const f32x4*)(src + u * 4);
    T[r][q * 16 + u * 4 + 0] = (__bf16)v[0];
    T[r][q * 16 + u * 4 + 1] = (__bf16)v[1];
    T[r][q * 16 + u * 4 + 2] = (__bf16)v[2];
    T[r][q * 16 + u * 4 + 3] = (__bf16)v[3];
  }
  __syncthreads();
  bf16x8 h0, h1;
#pragma unroll
  for (int u = 0; u < 8; ++u) {
    h0[u] = T[q * 16 + u][r];
    h1[u] = T[q * 16 + 8 + u][r];
  }
  __bf16* dst = Wt + (size_t)(bj * 64 + r) * 256 + bi * 64 + q * 16;
  *(bf16x8*)(dst)     = h0;
  *(bf16x8*)(dst + 8) = h1;
}

// ---- main GEMM template ----------------------------------------------------
// EPI_ST=true : St^T[b][n][m] bf16 epilogue (gemm1: feat @ W)
// EPI_ST=false: Out fp32 + bias epilogue, XCD-chunked swizzle (gemm2)
template <int KTOT, int LDA, int LDB, bool EPI_ST>
__global__ __launch_bounds__(512, 2) void k_gemm(
    const float* __restrict__ Aall, const __bf16* __restrict__ Bg_all,
    const float* __restrict__ bias, float* __restrict__ Out,
    __bf16* __restrict__ St) {
  __shared__ __bf16 As[2][128 * LDP];  // 36 KB
  __shared__ __bf16 Bs[2][256 * LDP];  // 72 KB

  const int tid  = threadIdx.x;
  const int lane = tid & 63;
  const int wv   = tid >> 6;
  const int wr   = wv >> 2;        // 0..1
  const int wc   = wv & 3;         // 0..3
  const int l16  = lane & 15;
  const int kch  = (lane >> 4) * 8;

  int lg, b;
  const float*  A;
  const __bf16* Bg;
  if constexpr (EPI_ST) {
    lg = blockIdx.x;
    b  = lg >> 3;
    A  = Aall + (size_t)lg * 128 * LDA;
    Bg = Bg_all;
  } else {
    const int h = blockIdx.x;               // 256 blocks, 256%8==0: bijective
    lg = (h & 7) * 32 + (h >> 3);           // batch-mates share one XCD's L2
    b  = lg >> 3;
    A  = Aall + (size_t)b * 1024 * 1024 + (size_t)(lg & 7) * 128 * LDA;
    Bg = Bg_all + (size_t)b * 256 * 1024;
  }

  // staging assignment: A 128x64 fp32 (64B/thr), B 256x64 bf16 (64B/thr)
  const int ar = tid >> 2;          // 0..127
  const int ac = (tid & 3) * 16;    // 0,16,32,48
  const int bn = tid >> 1;          // 0..255
  const int bc = (tid & 1) * 32;    // 0,32

  const float*  ap = A  + (size_t)ar * LDA + ac;
  const __bf16* bp = Bg + (size_t)bn * LDB + bc;

  f32x4  av[4];
  bf16x8 bv[4];

  auto load_regs = [&](int k0) {
#pragma unroll
    for (int u = 0; u < 4; ++u) av[u] = *(const f32x4*)(ap + k0 + u * 4);
#pragma unroll
    for (int u = 0; u < 4; ++u) bv[u] = *(const bf16x8*)(bp + k0 + u * 8);
  };
  auto cvt_write = [&](int buf) {
#pragma unroll
    for (int u = 0; u < 2; ++u) {
      bf16x8 h;
#pragma unroll
      for (int j = 0; j < 4; ++j) {
        h[j]     = (__bf16)av[2 * u][j];
        h[j + 4] = (__bf16)av[2 * u + 1][j];
      }
      *(bf16x8*)&As[buf][ar * LDP + ac + u * 8] = h;
    }
#pragma unroll
    for (int u = 0; u < 4; ++u)
      *(bf16x8*)&Bs[buf][bn * LDP + bc + u * 8] = bv[u];
  };

  f32x4 acc[4][4];
#pragma unroll
  for (int m = 0; m < 4; ++m)
#pragma unroll
    for (int n = 0; n < 4; ++n) acc[m][n] = (f32x4){0.f, 0.f, 0.f, 0.f};

  auto compute = [&](int buf) {
#pragma unroll
    for (int ks = 0; ks < 2; ++ks) {
      bf16x8 af[4], bfv[4];
#pragma unroll
      for (int m = 0; m < 4; ++m)
        af[m] = *(const bf16x8*)&As[buf][(wr * 64 + m * 16 + l16) * LDP + ks * 32 + kch];
#pragma unroll
      for (int n = 0; n < 4; ++n)
        bfv[n] = *(const bf16x8*)&Bs[buf][(wc * 64 + n * 16 + l16) * LDP + ks * 32 + kch];
#pragma unroll
      for (int m = 0; m < 4; ++m)
#pragma unroll
        for (int n = 0; n < 4; ++n)
          acc[m][n] = __builtin_amdgcn_mfma_f32_16x16x32_bf16(af[m], bfv[n], acc[m][n], 0, 0, 0);
    }
  };

  constexpr int NT = KTOT / 64;
  // prologue: stage tile 0
  load_regs(0);
  cvt_write(0);
  __syncthreads();
  int cur = 0;
#pragma unroll 2
  for (int t = 0; t < NT - 1; ++t) {
    load_regs((t + 1) * 64);   // issue early: HBM latency hides under MFMA
    compute(cur);
    cvt_write(cur ^ 1);        // compiler inserts vmcnt wait here, post-MFMA
    __syncthreads();
    cur ^= 1;
  }
  compute(cur);  // last tile, no barrier needed before global epilogue

  // epilogue. C/D frag: col = lane&15, row = (lane>>4)*4 + reg
  const int rg = (lane >> 4) * 4;
  if constexpr (EPI_ST) {
    const int mbase = (lg & 7) * 128;
#pragma unroll
    for (int n = 0; n < 4; ++n) {
      const int col = wc * 64 + n * 16 + l16;
      __bf16* dst = St + ((size_t)b * 256 + col) * 1024 + mbase;
#pragma unroll
      for (int m = 0; m < 4; ++m) {
        const int row = wr * 64 + m * 16 + rg;
        bf16x4 hh = {(__bf16)acc[m][n][0], (__bf16)acc[m][n][1],
                     (__bf16)acc[m][n][2], (__bf16)acc[m][n][3]};
        *(bf16x4*)(dst + row) = hh;
      }
    }
  } else {
    float* ob = Out + ((size_t)b * 1024 + (lg & 7) * 128) * 256;
#pragma unroll
    for (int n = 0; n < 4; ++n) {
      const int col = wc * 64 + n * 16 + l16;
      const float bvs = bias[col];
#pragma unroll
      for (int m = 0; m < 4; ++m) {
        const int row = wr * 64 + m * 16 + rg;
#pragma unroll
        for (int r2 = 0; r2 < 4; ++r2)
          ob[(size_t)(row + r2) * 256 + col] = acc[m][n][r2] + bvs;
      }
    }
  }
}

extern "C" void kernel_launch(void* const* d_in, const int* in_sizes, int n_in,
                              void* d_out, int out_size, void* d_ws, size_t ws_size,
                              hipStream_t stream) {
  const float* adj  = (const float*)d_in[0];
  const float* feat = (const float*)d_in[1];
  const float* w    = (const float*)d_in[2];
  const float* bias = (const float*)d_in[3];
  float* out = (float*)d_out;

  __bf16* Wt = (__bf16*)d_ws;                    // 128 KB
  __bf16* St = (__bf16*)((char*)d_ws + 131072);  // 16.78 MB

  k_wt<<<16, 256, 0, stream>>>(w, Wt);
  // gemm1: St^T = (feat @ W)^T   (K=256, A ld 256, B=Wt ld 256)
  k_gemm<256, 256, 256, true><<<256, 512, 0, stream>>>(feat, Wt, nullptr, nullptr, St);
  // gemm2: out = adj @ support + bias  (K=1024, A ld 1024, B=St ld 1024)
  k_gemm<1024, 1024, 1024, false><<<256, 512, 0, stream>>>(adj, St, bias, out, nullptr);
}

// Round 3
// 61.677 us; speedup vs baseline: 1.1314x; 1.0733x over previous
//
#include <hip/hip_runtime.h>
#include <hip/hip_bf16.h>

// GraphConvolution: out[b] = adj[b] @ (feat[b] @ W) + bias
// B=32, N=1024, IN=256, OUT=256. fp32 in/out, bf16 MFMA internally.
//
// ws: [0,128KB) Wt = W^T bf16 [n=256][k=256]
//     [128KB..) St = support^T bf16 [b][n=256][m=1024]
//
// GEMM template: 64x256 block tile, BK=32, 512 thr (8 waves, 2x4),
// LDS double-buffer (50 KB -> 2 blocks/CU) + depth-2 register prefetch
// (counted vmcnt: ds_write of tile t+1 waits vmcnt(3), tile t+2 stays in
// flight across every barrier). LDS rows padded to 40 el (80 B): bank-slot
// (l16*5+g) mod 8 is balanced -> conflict-free ds_read_b128.

typedef __attribute__((__ext_vector_type__(4))) float  f32x4;
typedef __attribute__((__ext_vector_type__(8))) __bf16 bf16x8;
typedef __attribute__((__ext_vector_type__(4))) __bf16 bf16x4;

#define BM  64
#define BN  256
#define BK  32
#define LDP 40

// ---- weight transpose: w[k][n] fp32 -> Wt[n][k] bf16 -----------------------
__global__ __launch_bounds__(256) void k_wt(const float* __restrict__ w,
                                            __bf16* __restrict__ Wt) {
  __shared__ __bf16 T[64][65];
  const int bi = blockIdx.x >> 2;
  const int bj = blockIdx.x & 3;
  const int t  = threadIdx.x;
  const int r  = t >> 2;
  const int q  = t & 3;
  const float* src = w + (size_t)(bi * 64 + r) * 256 + bj * 64 + q * 16;
#pragma unroll
  for (int u = 0; u < 4; ++u) {
    f32x4 v = *(const f32x4*)(src + u * 4);
    T[r][q * 16 + u * 4 + 0] = (__bf16)v[0];
    T[r][q * 16 + u * 4 + 1] = (__bf16)v[1];
    T[r][q * 16 + u * 4 + 2] = (__bf16)v[2];
    T[r][q * 16 + u * 4 + 3] = (__bf16)v[3];
  }
  __syncthreads();
  bf16x8 h0, h1;
#pragma unroll
  for (int u = 0; u < 8; ++u) {
    h0[u] = T[q * 16 + u][r];
    h1[u] = T[q * 16 + 8 + u][r];
  }
  __bf16* dst = Wt + (size_t)(bj * 64 + r) * 256 + bi * 64 + q * 16;
  *(bf16x8*)(dst)     = h0;
  *(bf16x8*)(dst + 8) = h1;
}

// ---- main GEMM template ----------------------------------------------------
// EPI_ST=true : St^T[b][n][m] bf16 epilogue (gemm1: feat @ W)
// EPI_ST=false: Out fp32 + bias epilogue, XCD-chunked swizzle (gemm2)
template <int KTOT, int LDA, int LDB, bool EPI_ST>
__global__ __launch_bounds__(512, 4) void k_gemm(
    const float* __restrict__ Aall, const __bf16* __restrict__ Bg_all,
    const float* __restrict__ bias, float* __restrict__ Out,
    __bf16* __restrict__ St) {
  __shared__ __bf16 As[2][BM * LDP];  // 10 KB
  __shared__ __bf16 Bs[2][BN * LDP];  // 40 KB

  const int tid  = threadIdx.x;
  const int lane = tid & 63;
  const int wv   = tid >> 6;
  const int wr   = wv >> 2;        // 0..1 -> 32 rows each
  const int wc   = wv & 3;         // 0..3 -> 64 cols each
  const int l16  = lane & 15;
  const int kch  = (lane >> 4) * 8;

  int lg, b, mtile;
  const float*  A;
  const __bf16* Bg;
  if constexpr (EPI_ST) {
    lg    = blockIdx.x;            // 512 blocks: 16 m-tiles x 32 batches
    b     = lg >> 4;
    mtile = lg & 15;
    A     = Aall + (size_t)lg * BM * LDA;  // feat rows are globally contiguous
    Bg    = Bg_all;
  } else {
    const int h = blockIdx.x;      // 512 % 8 == 0: bijective XCD swizzle
    lg    = (h & 7) * 64 + (h >> 3);  // XCD x owns batches 4x..4x+3 (L2 reuse of St)
    b     = lg >> 4;
    mtile = lg & 15;
    A     = Aall + (size_t)b * 1024 * 1024 + (size_t)mtile * BM * LDA;
    Bg    = Bg_all + (size_t)b * 256 * 1024;
  }

  // staging: A 64x32 fp32 (16 B/thr), B 256x32 bf16 (32 B/thr)
  const int ar = tid >> 3;          // 0..63
  const int ac = (tid & 7) * 4;     // 0..28
  const int br = tid >> 1;          // 0..255
  const int bh = (tid & 1) * 16;    // 0,16

  const float*  ap = A  + (size_t)ar * LDA + ac;
  const __bf16* bp = Bg + (size_t)br * LDB + bh;

  f32x4  av0, av1;
  bf16x8 bv0[2], bv1[2];

#define LOAD0(k0)                                   \
  av0    = *(const f32x4*)(ap + (k0));              \
  bv0[0] = *(const bf16x8*)(bp + (k0));             \
  bv0[1] = *(const bf16x8*)(bp + (k0) + 8)
#define LOAD1(k0)                                   \
  av1    = *(const f32x4*)(ap + (k0));              \
  bv1[0] = *(const bf16x8*)(bp + (k0));             \
  bv1[1] = *(const bf16x8*)(bp + (k0) + 8)

  auto cvt_write = [&](const f32x4& av, const bf16x8* bv, int buf) {
    bf16x4 h = {(__bf16)av[0], (__bf16)av[1], (__bf16)av[2], (__bf16)av[3]};
    *(bf16x4*)&As[buf][ar * LDP + ac]      = h;
    *(bf16x8*)&Bs[buf][br * LDP + bh]      = bv[0];
    *(bf16x8*)&Bs[buf][br * LDP + bh + 8]  = bv[1];
  };

  f32x4 acc[2][4];
#pragma unroll
  for (int m = 0; m < 2; ++m)
#pragma unroll
    for (int n = 0; n < 4; ++n) acc[m][n] = (f32x4){0.f, 0.f, 0.f, 0.f};

  auto compute = [&](int buf) {
    bf16x8 af[2], bfv[4];
#pragma unroll
    for (int m = 0; m < 2; ++m)
      af[m] = *(const bf16x8*)&As[buf][(wr * 32 + m * 16 + l16) * LDP + kch];
#pragma unroll
    for (int n = 0; n < 4; ++n)
      bfv[n] = *(const bf16x8*)&Bs[buf][(wc * 64 + n * 16 + l16) * LDP + kch];
#pragma unroll
    for (int m = 0; m < 2; ++m)
#pragma unroll
      for (int n = 0; n < 4; ++n)
        acc[m][n] = __builtin_amdgcn_mfma_f32_16x16x32_bf16(af[m], bfv[n], acc[m][n], 0, 0, 0);
  };

  constexpr int NT = KTOT / BK;  // 8 (gemm1) or 32 (gemm2); NT-2 even
  // prologue: tiles 0,1 in flight; tile 0 -> LDS buf0
  LOAD0(0);
  LOAD1(BK);
  cvt_write(av0, bv0, 0);  // waits only av0/bv0 (vmcnt(3)): tile 1 stays in flight
  __syncthreads();

  for (int t = 0; t < NT - 2; t += 2) {
    LOAD0((t + 2) * BK);           // issue tile t+2 before compute
    compute(0);
    cvt_write(av1, bv1, 1);        // vmcnt(3): tile t+2 remains in flight
    __syncthreads();
    LOAD1((t + 3) * BK);
    compute(1);
    cvt_write(av0, bv0, 0);
    __syncthreads();
  }
  compute(0);                      // tile NT-2
  cvt_write(av1, bv1, 1);
  __syncthreads();
  compute(1);                      // tile NT-1

#undef LOAD0
#undef LOAD1

  // epilogue. C/D frag: col = lane&15, row = (lane>>4)*4 + reg
  const int rg = (lane >> 4) * 4;
  if constexpr (EPI_ST) {
    const int mbase = mtile * BM;
#pragma unroll
    for (int n = 0; n < 4; ++n) {
      const int col = wc * 64 + n * 16 + l16;
      __bf16* dst = St + ((size_t)b * 256 + col) * 1024 + mbase;
#pragma unroll
      for (int m = 0; m < 2; ++m) {
        const int row = wr * 32 + m * 16 + rg;
        bf16x4 hh = {(__bf16)acc[m][n][0], (__bf16)acc[m][n][1],
                     (__bf16)acc[m][n][2], (__bf16)acc[m][n][3]};
        *(bf16x4*)(dst + row) = hh;
      }
    }
  } else {
    float* ob = Out + ((size_t)b * 1024 + (size_t)mtile * BM) * 256;
#pragma unroll
    for (int n = 0; n < 4; ++n) {
      const int col = wc * 64 + n * 16 + l16;
      const float bvs = bias[col];
#pragma unroll
      for (int m = 0; m < 2; ++m) {
        const int row = wr * 32 + m * 16 + rg;
#pragma unroll
        for (int r2 = 0; r2 < 4; ++r2)
          ob[(size_t)(row + r2) * 256 + col] = acc[m][n][r2] + bvs;
      }
    }
  }
}

extern "C" void kernel_launch(void* const* d_in, const int* in_sizes, int n_in,
                              void* d_out, int out_size, void* d_ws, size_t ws_size,
                              hipStream_t stream) {
  const float* adj  = (const float*)d_in[0];
  const float* feat = (const float*)d_in[1];
  const float* w    = (const float*)d_in[2];
  const float* bias = (const float*)d_in[3];
  float* out = (float*)d_out;

  __bf16* Wt = (__bf16*)d_ws;                    // 128 KB
  __bf16* St = (__bf16*)((char*)d_ws + 131072);  // 16.78 MB

  k_wt<<<16, 256, 0, stream>>>(w, Wt);
  // gemm1: St^T = (feat @ W)^T   (K=256, A ld 256, B=Wt ld 256), 512 blocks
  k_gemm<256, 256, 256, true><<<512, 512, 0, stream>>>(feat, Wt, nullptr, nullptr, St);
  // gemm2: out = adj @ support + bias  (K=1024), 512 blocks, XCD-swizzled
  k_gemm<1024, 1024, 1024, false><<<512, 512, 0, stream>>>(adj, St, bias, out, nullptr);
}

// Round 4
// 54.371 us; speedup vs baseline: 1.2834x; 1.1344x over previous
//
#include <hip/hip_runtime.h>
#include <hip/hip_bf16.h>

// GraphConvolution: out[b] = adj[b] @ (feat[b] @ W) + bias
// B=32, N=1024, IN=256, OUT=256. fp32 in/out, bf16 MFMA internally.
//
// ws: [0,128KB)  Wt = W^T bf16, k-subtiled: [k-chunk=k/8][n=256][8]
//     [128KB..)  St = support bf16, k-subtiled per batch:
//                 [b][m-chunk=m/8][n=256][8]   (m is gemm2's K dim)
//
// GEMM structure (m97-style): 64x256 tile, BK=32, 512 thr (8 waves 2x4),
// double-buffered LDS staged ONLY via global_load_lds (async DMA, stays in
// flight until the compiler's vmcnt(0)-before-barrier — pinned, cannot be
// sunk like register loads were in rounds 2-3).
//  - B tiles are contiguous 16 KB in memory (k-subtiled layout) -> linear DMA;
//    LDS [4][256][8] -> 16-B lane-stride ds_read_b128 (conflict-free).
//  - A staged as fp32 [64][32] with XOR slot^(row&7) swizzle applied on the
//    per-lane GLOBAL source (dest linear per rule #21); cvt fp32->bf16 on the
//    read side. Swizzled read: 8 distinct bank-quads per 8-lane group.

typedef __attribute__((__ext_vector_type__(4))) float  f32x4;
typedef __attribute__((__ext_vector_type__(8))) __bf16 bf16x8;
typedef __attribute__((__ext_vector_type__(4))) __bf16 bf16x4;

#define BM 64
#define BN 256
#define BK 32

__device__ __forceinline__ void gld16(const void* g, void* l) {
  __builtin_amdgcn_global_load_lds(
      (const __attribute__((address_space(1))) unsigned int*)g,
      (__attribute__((address_space(3))) unsigned int*)l, 16, 0, 0);
}

// ---- weight transpose: w[k][n] fp32 -> Wt k-subtiled [k/8][n][8] bf16 ------
__global__ __launch_bounds__(256) void k_wt(const float* __restrict__ w,
                                            __bf16* __restrict__ Wt) {
  __shared__ __bf16 T[64][65];
  const int bi = blockIdx.x >> 2;  // k tile
  const int bj = blockIdx.x & 3;   // n tile
  const int t  = threadIdx.x;
  const int r  = t >> 2;
  const int q  = t & 3;
  const float* src = w + (size_t)(bi * 64 + r) * 256 + bj * 64 + q * 16;
#pragma unroll
  for (int u = 0; u < 4; ++u) {
    f32x4 v = *(const f32x4*)(src + u * 4);
    T[r][q * 16 + u * 4 + 0] = (__bf16)v[0];
    T[r][q * 16 + u * 4 + 1] = (__bf16)v[1];
    T[r][q * 16 + u * 4 + 2] = (__bf16)v[2];
    T[r][q * 16 + u * 4 + 3] = (__bf16)v[3];
  }
  __syncthreads();
  bf16x8 h0, h1;
#pragma unroll
  for (int u = 0; u < 8; ++u) {
    h0[u] = T[q * 16 + u][r];      // k = bi*64+q*16+u,   n = bj*64+r
    h1[u] = T[q * 16 + 8 + u][r];  // k = bi*64+q*16+8+u
  }
  // element (n,k) -> [(k>>3)*256 + n]*8 + (k&7)
  __bf16* d0 = Wt + ((size_t)(bi * 8 + q * 2) * 256 + (bj * 64 + r)) * 8;
  *(bf16x8*)d0          = h0;
  *(bf16x8*)(d0 + 2048) = h1;  // next k-chunk
}

// ---- main GEMM template ----------------------------------------------------
// EPI_ST=true : epilogue -> St k-subtiled bf16 (gemm1: feat @ W)
// EPI_ST=false: epilogue -> Out fp32 + bias, XCD swizzle (gemm2: adj @ sup)
template <int KTOT, int LDA, bool EPI_ST>
__global__ __launch_bounds__(512, 4) void k_gemm(
    const float* __restrict__ Aall, const __bf16* __restrict__ Bg_all,
    const float* __restrict__ bias, float* __restrict__ Out,
    __bf16* __restrict__ St) {
  __shared__ float  Af[2][BM * BK];      // 8 KB each, slot-swizzled rows
  __shared__ __bf16 Bf[2][4 * BN * 8];   // 16 KB each, [chunk][n][8]

  const int tid  = threadIdx.x;
  const int lane = tid & 63;
  const int wid  = tid >> 6;
  const int wr   = wid >> 2;       // 0..1 -> 32 rows
  const int wc   = wid & 3;        // 0..3 -> 64 cols
  const int l16  = lane & 15;
  const int g    = lane >> 4;      // k-chunk 0..3

  int b, mtile;
  const float*  Ablk;
  const __bf16* Bblk;
  if constexpr (EPI_ST) {
    const int lg = blockIdx.x;     // 512 blocks: 32 batches x 16 m-tiles
    b     = lg >> 4;
    mtile = lg & 15;
    Ablk  = Aall + (size_t)lg * BM * LDA;   // feat rows globally contiguous
    Bblk  = Bg_all;                          // Wt, shared
  } else {
    const int h  = blockIdx.x;     // 512 % 8 == 0: bijective XCD swizzle
    const int lg = (h & 7) * 64 + (h >> 3);  // XCD x owns batches 4x..4x+3
    b     = lg >> 4;
    mtile = lg & 15;
    Ablk  = Aall + (size_t)b * 1024 * 1024 + (size_t)mtile * BM * LDA;
    Bblk  = Bg_all + (size_t)b * 262144;     // St[b], k-subtiled
  }

  // --- staging addresses ---
  // A: thread t stages 16 B -> LDS byte t*16 (linear); row r=t>>3, slot t&7;
  //    source column swizzled: k-slot = (t&7) ^ (r&7)
  const int    ar   = tid >> 3;
  const float* asrc = Ablk + (size_t)ar * LDA + (((tid & 7) ^ (ar & 7)) << 2);
  // B: wave w stages chunks [w*128, w*128+128): two 1-KB DMAs
  const __bf16* bs0 = Bblk + ((size_t)wid * 128 + lane) * 8;

  auto stage = [&](int buf, int k0) {
    gld16(asrc + k0, &Af[buf][wid * 256]);
    const __bf16* bt = bs0 + (size_t)(k0 >> 3) * 2048;
    gld16(bt,       &Bf[buf][wid * 1024]);
    gld16(bt + 512, &Bf[buf][wid * 1024 + 512]);
  };

  f32x4 acc[2][4];
#pragma unroll
  for (int m = 0; m < 2; ++m)
#pragma unroll
    for (int n = 0; n < 4; ++n) acc[m][n] = (f32x4){0.f, 0.f, 0.f, 0.f};

  const int h7 = l16 & 7;
  auto compute = [&](int buf) {
    bf16x8 af[2], bv[4];
#pragma unroll
    for (int m = 0; m < 2; ++m) {
      const float* base = &Af[buf][(wr * 32 + m * 16 + l16) * BK];
      f32x4 v0 = *(const f32x4*)(base + (((2 * g)     ^ h7) << 2));
      f32x4 v1 = *(const f32x4*)(base + (((2 * g + 1) ^ h7) << 2));
      af[m] = (bf16x8){(__bf16)v0[0], (__bf16)v0[1], (__bf16)v0[2], (__bf16)v0[3],
                       (__bf16)v1[0], (__bf16)v1[1], (__bf16)v1[2], (__bf16)v1[3]};
    }
#pragma unroll
    for (int n = 0; n < 4; ++n)
      bv[n] = *(const bf16x8*)&Bf[buf][(g * 256 + wc * 64 + n * 16 + l16) * 8];
#pragma unroll
    for (int m = 0; m < 2; ++m)
#pragma unroll
      for (int n = 0; n < 4; ++n)
        acc[m][n] = __builtin_amdgcn_mfma_f32_16x16x32_bf16(af[m], bv[n], acc[m][n], 0, 0, 0);
  };

  constexpr int NT = KTOT / BK;  // 8 or 32 (even)
  stage(0, 0);
  __syncthreads();               // compiler drains vmcnt(0) -> tile 0 ready
  for (int t = 0; t < NT - 2; t += 2) {
    stage(1, (t + 1) * BK);      // async DMA stays in flight under compute
    compute(0);
    __syncthreads();
    stage(0, (t + 2) * BK);
    compute(1);
    __syncthreads();
  }
  stage(1, (NT - 1) * BK);
  compute(0);
  __syncthreads();
  compute(1);

  // --- epilogue. C/D frag: col = lane&15, row = (lane>>4)*4 + reg ---
  const int rg = (lane >> 4) * 4;
  if constexpr (EPI_ST) {
    __bf16* Stb = St + (size_t)b * 262144;
#pragma unroll
    for (int n = 0; n < 4; ++n) {
      const int col = wc * 64 + n * 16 + l16;
#pragma unroll
      for (int m = 0; m < 2; ++m) {
        const int gm = mtile * 64 + wr * 32 + m * 16 + rg;  // multiple of 4
        __bf16* dst = Stb + ((size_t)(gm >> 3) * 256 + col) * 8 + (gm & 7);
        bf16x4 hh = {(__bf16)acc[m][n][0], (__bf16)acc[m][n][1],
                     (__bf16)acc[m][n][2], (__bf16)acc[m][n][3]};
        *(bf16x4*)dst = hh;
      }
    }
  } else {
    float* ob = Out + ((size_t)b * 1024 + (size_t)mtile * BM) * 256;
#pragma unroll
    for (int n = 0; n < 4; ++n) {
      const int col = wc * 64 + n * 16 + l16;
      const float bvs = bias[col];
#pragma unroll
      for (int m = 0; m < 2; ++m) {
        const int row = wr * 32 + m * 16 + rg;
#pragma unroll
        for (int r2 = 0; r2 < 4; ++r2)
          ob[(size_t)(row + r2) * 256 + col] = acc[m][n][r2] + bvs;
      }
    }
  }
}

extern "C" void kernel_launch(void* const* d_in, const int* in_sizes, int n_in,
                              void* d_out, int out_size, void* d_ws, size_t ws_size,
                              hipStream_t stream) {
  const float* adj  = (const float*)d_in[0];
  const float* feat = (const float*)d_in[1];
  const float* w    = (const float*)d_in[2];
  const float* bias = (const float*)d_in[3];
  float* out = (float*)d_out;

  __bf16* Wt = (__bf16*)d_ws;                    // 128 KB
  __bf16* St = (__bf16*)((char*)d_ws + 131072);  // 16.78 MB

  k_wt<<<16, 256, 0, stream>>>(w, Wt);
  // gemm1: St = (feat @ W) in k-subtiled layout  (K=256, A ld 256)
  k_gemm<256, 256, true><<<512, 512, 0, stream>>>(feat, Wt, nullptr, nullptr, St);
  // gemm2: out = adj @ support + bias            (K=1024, A ld 1024)
  k_gemm<1024, 1024, false><<<512, 512, 0, stream>>>(adj, St, bias, out, nullptr);
}